// Round 1
// baseline (220.976 us; speedup 1.0000x reference)
//
#include <hip/hip_runtime.h>

constexpr int N_      = 2048;
constexpr int IN_DIM  = 512;
constexpr int HID     = 512;
constexpr int EMB     = 256;
constexpr int M_      = 256;

// ---------------------------------------------------------------------------
// t_emb[m,d] = E_pred[t0][d] + E_filt[t1][d] + E_reo[t2][d]
// ---------------------------------------------------------------------------
__global__ __launch_bounds__(256)
void gather_temb(const int* __restrict__ tuples,
                 const float* __restrict__ Ep,
                 const float* __restrict__ Ef,
                 const float* __restrict__ Er,
                 float* __restrict__ t_emb)
{
    const int m = blockIdx.x;
    const int d = threadIdx.x;
    const int t0 = tuples[m * 3 + 0];
    const int t1 = tuples[m * 3 + 1];
    const int t2 = tuples[m * 3 + 2];
    t_emb[m * EMB + d] = Ep[t0 * EMB + d] + Ef[t1 * EMB + d] + Er[t2 * EMB + d];
}

// ---------------------------------------------------------------------------
// Generic NT GEMM: C[r, c] = act( sum_k A[r,k] * W[c,k] + bias[c] )
// A: (rows, K) row-major lda;  W: (cols, K) row-major ldw.
// Block tile BM x BN, 256 threads (16x16), micro-tile (BM/16)x(BN/16).
// ---------------------------------------------------------------------------
template<int BM, int BN, int BK, bool RELU, bool BIAS>
__global__ __launch_bounds__(256)
void gemm_nt(const float* __restrict__ A, int lda,
             const float* __restrict__ W, int ldw,
             const float* __restrict__ bias,
             float* __restrict__ C, int ldc, int K)
{
    constexpr int WM = BM / 16;
    constexpr int WN = BN / 16;
    __shared__ __align__(16) float As[BK][BM + 4];
    __shared__ __align__(16) float Ws[BK][BN + 4];

    const int tid = threadIdx.x;
    const int tx = tid & 15, ty = tid >> 4;
    const int row0 = blockIdx.x * BM;
    const int col0 = blockIdx.y * BN;

    float acc[WM][WN];
#pragma unroll
    for (int i = 0; i < WM; ++i)
#pragma unroll
        for (int j = 0; j < WN; ++j) acc[i][j] = 0.f;

    for (int k0 = 0; k0 < K; k0 += BK) {
#pragma unroll
        for (int idx = tid; idx < BM * BK / 4; idx += 256) {
            const int r  = idx / (BK / 4);
            const int c4 = idx % (BK / 4);
            const float4 v = *(const float4*)&A[(size_t)(row0 + r) * lda + k0 + c4 * 4];
            As[c4 * 4 + 0][r] = v.x;
            As[c4 * 4 + 1][r] = v.y;
            As[c4 * 4 + 2][r] = v.z;
            As[c4 * 4 + 3][r] = v.w;
        }
#pragma unroll
        for (int idx = tid; idx < BN * BK / 4; idx += 256) {
            const int r  = idx / (BK / 4);
            const int c4 = idx % (BK / 4);
            const float4 v = *(const float4*)&W[(size_t)(col0 + r) * ldw + k0 + c4 * 4];
            Ws[c4 * 4 + 0][r] = v.x;
            Ws[c4 * 4 + 1][r] = v.y;
            Ws[c4 * 4 + 2][r] = v.z;
            Ws[c4 * 4 + 3][r] = v.w;
        }
        __syncthreads();
#pragma unroll
        for (int k = 0; k < BK; ++k) {
            float a[WM], b[WN];
#pragma unroll
            for (int i = 0; i < WM; ++i) a[i] = As[k][ty * WM + i];
#pragma unroll
            for (int j = 0; j < WN; ++j) b[j] = Ws[k][tx * WN + j];
#pragma unroll
            for (int i = 0; i < WM; ++i)
#pragma unroll
                for (int j = 0; j < WN; ++j)
                    acc[i][j] = fmaf(a[i], b[j], acc[i][j]);
        }
        __syncthreads();
    }

#pragma unroll
    for (int i = 0; i < WM; ++i) {
#pragma unroll
        for (int j = 0; j < WN; ++j) {
            float v = acc[i][j];
            if (BIAS) v += bias[col0 + tx * WN + j];
            if (RELU) v = fmaxf(v, 0.f);
            C[(size_t)(row0 + ty * WM + i) * ldc + col0 + tx * WN + j] = v;
        }
    }
}

// ---------------------------------------------------------------------------
// out[n,m] = sum_h relu(hx[n,h] + cm[m,h]) * w2[h] + b2
// Tile: 32 n x 64 m per block, 256 threads, 2x4 micro-tile, BK=32 h-chunk,
// double-buffered LDS with register prefetch (1 barrier per chunk).
// ---------------------------------------------------------------------------
__global__ __launch_bounds__(256)
void fused_out(const float* __restrict__ hx,
               const float* __restrict__ cm,
               const float* __restrict__ w2,
               const float* __restrict__ b2,
               float* __restrict__ out)
{
    constexpr int TN = 32, TM = 64, BK = 32;
    constexpr int NCHUNK = HID / BK;  // 16
    __shared__ __align__(16) float Hs[2][BK][TN + 4];
    __shared__ __align__(16) float Cs[2][BK][TM + 4];
    __shared__ __align__(16) float wsh[2][BK];

    const int tid = threadIdx.x;
    const int tx = tid & 15, ty = tid >> 4;
    const int n0 = blockIdx.x * TN;
    const int m0 = blockIdx.y * TM;

    // load coords: row = tid/8 (0..31), col4 = tid%8
    const int lr  = tid >> 3;
    const int lc4 = tid & 7;

    float4 pa, pc0, pc1;
    float  pw;

    auto issue = [&](int k0) {
        pa  = *(const float4*)&hx[(size_t)(n0 + lr) * HID + k0 + lc4 * 4];
        pc0 = *(const float4*)&cm[(size_t)(m0 + lr) * HID + k0 + lc4 * 4];
        pc1 = *(const float4*)&cm[(size_t)(m0 + lr + 32) * HID + k0 + lc4 * 4];
        pw  = (tid < BK) ? w2[k0 + tid] : 0.f;
    };
    auto store = [&](int buf) {
        Hs[buf][lc4 * 4 + 0][lr] = pa.x;
        Hs[buf][lc4 * 4 + 1][lr] = pa.y;
        Hs[buf][lc4 * 4 + 2][lr] = pa.z;
        Hs[buf][lc4 * 4 + 3][lr] = pa.w;
        Cs[buf][lc4 * 4 + 0][lr] = pc0.x;
        Cs[buf][lc4 * 4 + 1][lr] = pc0.y;
        Cs[buf][lc4 * 4 + 2][lr] = pc0.z;
        Cs[buf][lc4 * 4 + 3][lr] = pc0.w;
        Cs[buf][lc4 * 4 + 0][lr + 32] = pc1.x;
        Cs[buf][lc4 * 4 + 1][lr + 32] = pc1.y;
        Cs[buf][lc4 * 4 + 2][lr + 32] = pc1.z;
        Cs[buf][lc4 * 4 + 3][lr + 32] = pc1.w;
        if (tid < BK) wsh[buf][tid] = pw;
    };

    float acc[2][4];
#pragma unroll
    for (int i = 0; i < 2; ++i)
#pragma unroll
        for (int j = 0; j < 4; ++j) acc[i][j] = 0.f;

    issue(0);
    store(0);

    for (int c = 0; c < NCHUNK; ++c) {
        const int buf = c & 1;
        if (c + 1 < NCHUNK) issue((c + 1) * BK);
        __syncthreads();
#pragma unroll
        for (int h = 0; h < BK; ++h) {
            const float a0 = Hs[buf][h][ty * 2 + 0];
            const float a1 = Hs[buf][h][ty * 2 + 1];
            const float4 b = *(const float4*)&Cs[buf][h][tx * 4];
            const float wh = wsh[buf][h];
            acc[0][0] = fmaf(fmaxf(a0 + b.x, 0.f), wh, acc[0][0]);
            acc[0][1] = fmaf(fmaxf(a0 + b.y, 0.f), wh, acc[0][1]);
            acc[0][2] = fmaf(fmaxf(a0 + b.z, 0.f), wh, acc[0][2]);
            acc[0][3] = fmaf(fmaxf(a0 + b.w, 0.f), wh, acc[0][3]);
            acc[1][0] = fmaf(fmaxf(a1 + b.x, 0.f), wh, acc[1][0]);
            acc[1][1] = fmaf(fmaxf(a1 + b.y, 0.f), wh, acc[1][1]);
            acc[1][2] = fmaf(fmaxf(a1 + b.z, 0.f), wh, acc[1][2]);
            acc[1][3] = fmaf(fmaxf(a1 + b.w, 0.f), wh, acc[1][3]);
        }
        if (c + 1 < NCHUNK) store((c + 1) & 1);
    }

    const float bb = b2[0];
#pragma unroll
    for (int i = 0; i < 2; ++i) {
        float4 o;
        o.x = acc[i][0] + bb;
        o.y = acc[i][1] + bb;
        o.z = acc[i][2] + bb;
        o.w = acc[i][3] + bb;
        *(float4*)&out[(size_t)(n0 + ty * 2 + i) * M_ + m0 + tx * 4] = o;
    }
}

// ---------------------------------------------------------------------------
extern "C" void kernel_launch(void* const* d_in, const int* in_sizes, int n_in,
                              void* d_out, int out_size, void* d_ws, size_t ws_size,
                              hipStream_t stream)
{
    const float* x      = (const float*)d_in[0];
    const int*   tuples = (const int*)d_in[1];
    const float* Wa     = (const float*)d_in[2];
    const float* ba     = (const float*)d_in[3];
    const float* Wb     = (const float*)d_in[4];
    const float* bb     = (const float*)d_in[5];
    const float* E_pred = (const float*)d_in[6];
    const float* E_filt = (const float*)d_in[7];
    const float* E_reo  = (const float*)d_in[8];
    const float* W1     = (const float*)d_in[9];
    const float* b1     = (const float*)d_in[10];
    const float* W2     = (const float*)d_in[11];
    const float* b2     = (const float*)d_in[12];
    float* out = (float*)d_out;

    // workspace layout (floats). hx reuses the h_x slot (h_x dead after x_emb).
    float* ws    = (float*)d_ws;
    float* h_x   = ws;                       // 2048*512
    float* x_emb = h_x + N_ * HID;           // 2048*256
    float* hx    = ws;                       // 2048*512 (reuse)
    float* t_emb = x_emb + N_ * EMB;         // 256*256
    float* cmat  = t_emb + M_ * EMB;         // 256*512

    // t_emb gather, then cm[m,h] = sum_d t_emb[m,d]*W1t[h,d] + b1[h]
    gather_temb<<<dim3(M_), dim3(EMB), 0, stream>>>(tuples, E_pred, E_filt, E_reo, t_emb);
    gemm_nt<32, 64, 32, false, true><<<dim3(M_ / 32, HID / 64), 256, 0, stream>>>(
        t_emb, EMB, W1 + EMB, 2 * EMB, b1, cmat, HID, EMB);

    // h_x = relu(x @ Wa^T + ba)
    gemm_nt<64, 64, 32, true, true><<<dim3(N_ / 64, HID / 64), 256, 0, stream>>>(
        x, IN_DIM, Wa, IN_DIM, ba, h_x, HID, IN_DIM);

    // x_emb = relu(h_x @ Wb^T + bb)
    gemm_nt<64, 32, 32, true, true><<<dim3(N_ / 64, EMB / 32), 256, 0, stream>>>(
        h_x, HID, Wb, HID, bb, x_emb, EMB, HID);

    // hx = x_emb @ W1x^T   (no bias/relu; b1 folded into cmat)
    gemm_nt<64, 64, 32, false, false><<<dim3(N_ / 64, HID / 64), 256, 0, stream>>>(
        x_emb, EMB, W1, 2 * EMB, nullptr, hx, HID, EMB);

    // out[n,m] = sum_h relu(hx[n,h] + cmat[m,h]) * W2[h] + b2
    fused_out<<<dim3(N_ / 32, M_ / 64), 256, 0, stream>>>(hx, cmat, W2, b2, out);
}

// Round 2
// 167.247 us; speedup vs baseline: 1.3213x; 1.3213x over previous
//
#include <hip/hip_runtime.h>

constexpr int N_     = 2048;
constexpr int IN_DIM = 512;
constexpr int HID    = 512;
constexpr int EMB    = 256;
constexpr int M_     = 256;

typedef __attribute__((ext_vector_type(8))) short short8;
typedef __attribute__((ext_vector_type(4))) float f32x4;

__device__ __forceinline__ unsigned short f2bf(float f) {
    union { float f; unsigned int u; } v; v.f = f;
    return (unsigned short)((v.u + 0x7fffu + ((v.u >> 16) & 1u)) >> 16);
}

// ---------------------------------------------------------------------------
// t_emb[m,d] = E_pred[t0][d] + E_filt[t1][d] + E_reo[t2][d]   (fp32)
// ---------------------------------------------------------------------------
__global__ __launch_bounds__(256)
void gather_temb(const int* __restrict__ tuples,
                 const float* __restrict__ Ep,
                 const float* __restrict__ Ef,
                 const float* __restrict__ Er,
                 float* __restrict__ t_emb)
{
    const int m = blockIdx.x;
    const int d = threadIdx.x;
    const int t0 = tuples[m * 3 + 0];
    const int t1 = tuples[m * 3 + 1];
    const int t2 = tuples[m * 3 + 2];
    t_emb[m * EMB + d] = Ep[t0 * EMB + d] + Ef[t1 * EMB + d] + Er[t2 * EMB + d];
}

// ---------------------------------------------------------------------------
// bf16-MFMA NT GEMM: C[r,c] = act( sum_k A[r,k]*W[c,k] + bias )
// A fp32 (rows x K, lda), W fp32 (cols x K, ldw); fp32->bf16 RNE at staging;
// fp32 accumulate in MFMA; fp32 output. 256 threads = 4 waves (2x2 subtiles).
// ---------------------------------------------------------------------------
template<int BM, int BN, bool RELU, bool BIASC, bool BIASR>
__global__ __launch_bounds__(256)
void gemm_bf16(const float* __restrict__ A, int lda,
               const float* __restrict__ W, int ldw,
               const float* __restrict__ bias,
               float* __restrict__ C, int ldc, int K)
{
    constexpr int BK = 64;
    constexpr int SM = BM / 2, SN = BN / 2;
    constexpr int FM = SM / 16, FN = SN / 16;
    constexpr int AIT = BM / 16, WIT = BN / 16;
    __shared__ unsigned short As[BM][BK + 8];   // stride 144B, 16B-aligned rows
    __shared__ unsigned short Ws[BN][BK + 8];

    const int tid  = threadIdx.x;
    const int row0 = blockIdx.x * BM, col0 = blockIdx.y * BN;
    const int wv = tid >> 6, lane = tid & 63;
    const int wr = wv >> 1, wc = wv & 1;
    const int lr = lane & 15, lq = lane >> 4;

    f32x4 acc[FM][FN];
#pragma unroll
    for (int i = 0; i < FM; ++i)
#pragma unroll
        for (int j = 0; j < FN; ++j) acc[i][j] = (f32x4)0.f;

    float4 pa[AIT], pw[WIT];

    auto issue = [&](int k0) {
#pragma unroll
        for (int i = 0; i < AIT; ++i) {
            const int idx = tid + i * 256;
            const int r = idx >> 4, c4 = idx & 15;
            pa[i] = *(const float4*)&A[(size_t)(row0 + r) * lda + k0 + c4 * 4];
        }
#pragma unroll
        for (int i = 0; i < WIT; ++i) {
            const int idx = tid + i * 256;
            const int r = idx >> 4, c4 = idx & 15;
            pw[i] = *(const float4*)&W[(size_t)(col0 + r) * ldw + k0 + c4 * 4];
        }
    };
    auto store = [&]() {
#pragma unroll
        for (int i = 0; i < AIT; ++i) {
            const int idx = tid + i * 256;
            const int r = idx >> 4, c4 = idx & 15;
            ushort4 u;
            u.x = f2bf(pa[i].x); u.y = f2bf(pa[i].y);
            u.z = f2bf(pa[i].z); u.w = f2bf(pa[i].w);
            *(ushort4*)&As[r][c4 * 4] = u;
        }
#pragma unroll
        for (int i = 0; i < WIT; ++i) {
            const int idx = tid + i * 256;
            const int r = idx >> 4, c4 = idx & 15;
            ushort4 u;
            u.x = f2bf(pw[i].x); u.y = f2bf(pw[i].y);
            u.z = f2bf(pw[i].z); u.w = f2bf(pw[i].w);
            *(ushort4*)&Ws[r][c4 * 4] = u;
        }
    };

    issue(0);
    store();
    const int NC = K / BK;
    for (int c = 0; c < NC; ++c) {
        if (c + 1 < NC) issue((c + 1) * BK);
        __syncthreads();
#pragma unroll
        for (int ks = 0; ks < 2; ++ks) {
            short8 af[FM], bf[FN];
#pragma unroll
            for (int i = 0; i < FM; ++i)
                af[i] = *(const short8*)&As[wr * SM + i * 16 + lr][ks * 32 + lq * 8];
#pragma unroll
            for (int j = 0; j < FN; ++j)
                bf[j] = *(const short8*)&Ws[wc * SN + j * 16 + lr][ks * 32 + lq * 8];
#pragma unroll
            for (int i = 0; i < FM; ++i)
#pragma unroll
                for (int j = 0; j < FN; ++j)
                    acc[i][j] = __builtin_amdgcn_mfma_f32_16x16x32_bf16(
                        af[i], bf[j], acc[i][j], 0, 0, 0);
        }
        __syncthreads();
        if (c + 1 < NC) store();
    }

    // C/D layout: col = lane&15, row = (lane>>4)*4 + j
#pragma unroll
    for (int i = 0; i < FM; ++i) {
#pragma unroll
        for (int j = 0; j < FN; ++j) {
#pragma unroll
            for (int e = 0; e < 4; ++e) {
                const int row = row0 + wr * SM + i * 16 + lq * 4 + e;
                const int col = col0 + wc * SN + j * 16 + lr;
                float v = acc[i][j][e];
                if (BIASC) v += bias[col];
                if (BIASR) v += bias[row];
                if (RELU)  v = fmaxf(v, 0.f);
                C[(size_t)row * ldc + col] = v;
            }
        }
    }
}

// ---------------------------------------------------------------------------
// out[n,m] += sum_{h in half z} relu(hxT[h,n] + cmT[h,m]) * w2[h]  (+ b2, z=0)
// 1-wave blocks (64 thr), 4x4 micro-tile, tile 16n x 64m, BK=32 h-chunk,
// double-buffered reg prefetch, split-h x2 via fp32 atomicAdd.
// ---------------------------------------------------------------------------
__global__ __launch_bounds__(64)
void fused_out(const float* __restrict__ hxT,
               const float* __restrict__ cmT,
               const float* __restrict__ w2,
               const float* __restrict__ b2,
               float* __restrict__ out)
{
    constexpr int TN = 16, TM = 64, BK = 32;
    __shared__ __align__(16) float Hs[2][BK][TN + 4];
    __shared__ __align__(16) float Cs[2][BK][TM + 4];
    __shared__ __align__(16) float wsh[2][BK];

    const int l  = threadIdx.x;
    const int tx = l & 15, ty = l >> 4;        // m-quad, n-group
    const int n0 = blockIdx.x * TN;
    const int m0 = blockIdx.y * TM;
    const int kbase = blockIdx.z * (HID / 2);

    float4 ph[2], pc[8];
    float  pwv;

    auto issue = [&](int k0) {
#pragma unroll
        for (int i = 0; i < 2; ++i) {
            const int idx = l + i * 64;
            const int k = idx >> 2, c4 = idx & 3;
            ph[i] = *(const float4*)&hxT[(size_t)(kbase + k0 + k) * N_ + n0 + c4 * 4];
        }
#pragma unroll
        for (int i = 0; i < 8; ++i) {
            const int idx = l + i * 64;
            const int k = idx >> 4, c4 = idx & 15;
            pc[i] = *(const float4*)&cmT[(size_t)(kbase + k0 + k) * M_ + m0 + c4 * 4];
        }
        pwv = (l < BK) ? w2[kbase + k0 + l] : 0.f;
    };
    auto store = [&](int b) {
#pragma unroll
        for (int i = 0; i < 2; ++i) {
            const int idx = l + i * 64;
            const int k = idx >> 2, c4 = idx & 3;
            *(float4*)&Hs[b][k][c4 * 4] = ph[i];
        }
#pragma unroll
        for (int i = 0; i < 8; ++i) {
            const int idx = l + i * 64;
            const int k = idx >> 4, c4 = idx & 15;
            *(float4*)&Cs[b][k][c4 * 4] = pc[i];
        }
        if (l < BK) wsh[b][l] = pwv;
    };

    float acc[4][4];
#pragma unroll
    for (int i = 0; i < 4; ++i)
#pragma unroll
        for (int j = 0; j < 4; ++j) acc[i][j] = 0.f;

    issue(0);
    store(0);

    constexpr int NC = (HID / 2) / BK;  // 8
    for (int c = 0; c < NC; ++c) {
        const int buf = c & 1;
        if (c + 1 < NC) issue((c + 1) * BK);
        __syncthreads();
#pragma unroll
        for (int h4 = 0; h4 < BK / 4; ++h4) {
            const float4 wq = *(const float4*)&wsh[buf][h4 * 4];
            const float wv4[4] = {wq.x, wq.y, wq.z, wq.w};
#pragma unroll
            for (int hh = 0; hh < 4; ++hh) {
                const int h = h4 * 4 + hh;
                const float4 a = *(const float4*)&Hs[buf][h][ty * 4];
                const float4 b = *(const float4*)&Cs[buf][h][tx * 4];
                const float wh = wv4[hh];
                const float av[4] = {a.x, a.y, a.z, a.w};
                const float bv[4] = {b.x, b.y, b.z, b.w};
#pragma unroll
                for (int i = 0; i < 4; ++i)
#pragma unroll
                    for (int j = 0; j < 4; ++j)
                        acc[i][j] = fmaf(fmaxf(av[i] + bv[j], 0.f), wh, acc[i][j]);
            }
        }
        if (c + 1 < NC) store((c + 1) & 1);
    }

    const float bb = (blockIdx.z == 0) ? b2[0] : 0.f;
#pragma unroll
    for (int i = 0; i < 4; ++i)
#pragma unroll
        for (int j = 0; j < 4; ++j)
            atomicAdd(&out[(size_t)(n0 + ty * 4 + i) * M_ + m0 + tx * 4 + j],
                      acc[i][j] + bb);
}

// ---------------------------------------------------------------------------
extern "C" void kernel_launch(void* const* d_in, const int* in_sizes, int n_in,
                              void* d_out, int out_size, void* d_ws, size_t ws_size,
                              hipStream_t stream)
{
    const float* x      = (const float*)d_in[0];
    const int*   tuples = (const int*)d_in[1];
    const float* Wa     = (const float*)d_in[2];
    const float* ba     = (const float*)d_in[3];
    const float* Wb     = (const float*)d_in[4];
    const float* bb     = (const float*)d_in[5];
    const float* E_pred = (const float*)d_in[6];
    const float* E_filt = (const float*)d_in[7];
    const float* E_reo  = (const float*)d_in[8];
    const float* W1     = (const float*)d_in[9];
    const float* b1     = (const float*)d_in[10];
    const float* W2     = (const float*)d_in[11];
    const float* b2     = (const float*)d_in[12];
    float* out = (float*)d_out;

    // ws layout (floats); hxT reuses h_x slot (h_x dead after x_emb).
    float* ws    = (float*)d_ws;
    float* h_x   = ws;                       // 2048*512
    float* x_emb = h_x + N_ * HID;           // 2048*256
    float* t_emb = x_emb + N_ * EMB;         // 256*256
    float* cmT   = t_emb + M_ * EMB;         // 512*256  [h][m]
    float* hxT   = ws;                       // 512*2048 [h][n] (reuse)

    hipMemsetAsync(d_out, 0, (size_t)N_ * M_ * sizeof(float), stream);

    gather_temb<<<dim3(M_), dim3(EMB), 0, stream>>>(tuples, E_pred, E_filt, E_reo, t_emb);

    // h_x = relu(x @ Wa^T + ba)            (2048x512, K=512)  grid 64x8
    gemm_bf16<32, 64, true, true, false><<<dim3(N_ / 32, HID / 64), 256, 0, stream>>>(
        x, IN_DIM, Wa, IN_DIM, ba, h_x, HID, IN_DIM);

    // x_emb = relu(h_x @ Wb^T + bb)        (2048x256, K=512)  grid 64x4
    gemm_bf16<32, 64, true, true, false><<<dim3(N_ / 32, EMB / 64), 256, 0, stream>>>(
        h_x, HID, Wb, HID, bb, x_emb, EMB, HID);

    // cmT[h,m] = sum_d W1t[h,d]*t_emb[m,d] + b1[h]   (512x256, K=256) grid 16x4
    gemm_bf16<32, 64, false, false, true><<<dim3(HID / 32, M_ / 64), 256, 0, stream>>>(
        W1 + EMB, 2 * EMB, t_emb, EMB, b1, cmT, M_, EMB);

    // hxT[h,n] = sum_d W1x[h,d]*x_emb[n,d]           (512x2048, K=256) grid 16x32
    gemm_bf16<32, 64, false, false, false><<<dim3(HID / 32, N_ / 64), 256, 0, stream>>>(
        W1, 2 * EMB, x_emb, EMB, nullptr, hxT, N_, EMB);

    // out[n,m] = sum_h relu(hxT[h,n] + cmT[h,m]) * W2[h] + b2
    fused_out<<<dim3(N_ / 16, M_ / 64, 2), 64, 0, stream>>>(hxT, cmT, W2, b2, out);
}

// Round 3
// 164.285 us; speedup vs baseline: 1.3451x; 1.0180x over previous
//
#include <hip/hip_runtime.h>

constexpr int N_     = 2048;
constexpr int IN_DIM = 512;
constexpr int HID    = 512;
constexpr int EMB    = 256;
constexpr int M_     = 256;

typedef __attribute__((ext_vector_type(8))) short short8;
typedef __attribute__((ext_vector_type(4))) float f32x4;

__device__ __forceinline__ unsigned short f2bf(float f) {
    union { float f; unsigned int u; } v; v.f = f;
    return (unsigned short)((v.u + 0x7fffu + ((v.u >> 16) & 1u)) >> 16);
}
__device__ __forceinline__ float bf2f(unsigned short u) {
    union { unsigned int u; float f; } v; v.u = ((unsigned int)u) << 16;
    return v.f;
}

// ---------------------------------------------------------------------------
// prep: fp32->bf16 conversion of x, Wa, Wb, W1 (split W1x/W1t) + t_emb gather.
// Blocks [0,1664): conversions (float4 granules). Blocks [1664,1728): gather.
// ---------------------------------------------------------------------------
__global__ __launch_bounds__(256)
void prep(const float* __restrict__ x, const float* __restrict__ Wa,
          const float* __restrict__ Wb, const float* __restrict__ W1,
          const int* __restrict__ tuples, const float* __restrict__ Ep,
          const float* __restrict__ Ef, const float* __restrict__ Er,
          unsigned short* __restrict__ x_bf, unsigned short* __restrict__ Wa_bf,
          unsigned short* __restrict__ Wb_bf, unsigned short* __restrict__ W1x_bf,
          unsigned short* __restrict__ W1t_bf, unsigned short* __restrict__ t_emb_bf)
{
    const int b = blockIdx.x, t = threadIdx.x;
    if (b < 1664) {
        int q = b * 256 + t;
        float4 v;
        ushort4 u;
        if (q < 262144) {                       // x: 2048x512
            v = ((const float4*)x)[q];
            u.x = f2bf(v.x); u.y = f2bf(v.y); u.z = f2bf(v.z); u.w = f2bf(v.w);
            ((ushort4*)x_bf)[q] = u;
        } else if ((q -= 262144) < 65536) {     // Wa: 512x512
            v = ((const float4*)Wa)[q];
            u.x = f2bf(v.x); u.y = f2bf(v.y); u.z = f2bf(v.z); u.w = f2bf(v.w);
            ((ushort4*)Wa_bf)[q] = u;
        } else if ((q -= 65536) < 32768) {      // Wb: 256x512
            v = ((const float4*)Wb)[q];
            u.x = f2bf(v.x); u.y = f2bf(v.y); u.z = f2bf(v.z); u.w = f2bf(v.w);
            ((ushort4*)Wb_bf)[q] = u;
        } else {                                // W1: 512x512, split cols
            q -= 32768;
            v = ((const float4*)W1)[q];
            u.x = f2bf(v.x); u.y = f2bf(v.y); u.z = f2bf(v.z); u.w = f2bf(v.w);
            const int row = q >> 7, c = (q & 127) * 4;
            if (c < 256) ((ushort4*)W1x_bf)[(row * 256 + c) >> 2] = u;
            else         ((ushort4*)W1t_bf)[(row * 256 + c - 256) >> 2] = u;
        }
    } else {
        const int idx = (b - 1664) * 256 + t;   // 0..16383
        const int m = idx >> 6, q = idx & 63;
        const int t0 = tuples[m * 3 + 0];
        const int t1 = tuples[m * 3 + 1];
        const int t2 = tuples[m * 3 + 2];
        const float4 a = ((const float4*)(Ep + t0 * EMB))[q];
        const float4 c = ((const float4*)(Ef + t1 * EMB))[q];
        const float4 d = ((const float4*)(Er + t2 * EMB))[q];
        ushort4 u;
        u.x = f2bf(a.x + c.x + d.x);
        u.y = f2bf(a.y + c.y + d.y);
        u.z = f2bf(a.z + c.z + d.z);
        u.w = f2bf(a.w + c.w + d.w);
        ((ushort4*)t_emb_bf)[m * 64 + q] = u;
    }
}

// ---------------------------------------------------------------------------
// bf16-in MFMA NT GEMM: C[r,c] = act( sum_k A[r,k]*W[c,k] + bias )
// A,W bf16 (K-contig); out bf16 or fp32. 256 threads = 4 waves (2x2 subtiles),
// BK=64, reg-prefetch single-LDS-buffer (2 barriers/chunk), zero staging math.
// ---------------------------------------------------------------------------
template<int BM, int BN, bool OUTBF, bool RELU, bool BIASC, bool BIASR>
__global__ __launch_bounds__(256)
void gemm_bf16(const unsigned short* __restrict__ A, int lda,
               const unsigned short* __restrict__ W, int ldw,
               const float* __restrict__ bias,
               void* __restrict__ Cout, int ldc, int K)
{
    constexpr int BK = 64;
    constexpr int SM = BM / 2, SN = BN / 2;
    constexpr int FM = SM / 16, FN = SN / 16;
    constexpr int AIT = BM / 32, WIT = BN / 32;     // 16B loads per thread
    __shared__ unsigned short As[BM][BK + 8];       // 144B row stride
    __shared__ unsigned short Bs[BN][BK + 8];

    const int tid  = threadIdx.x;
    const int row0 = blockIdx.x * BM, col0 = blockIdx.y * BN;
    const int wv = tid >> 6, lane = tid & 63;
    const int wr = wv >> 1, wc = wv & 1;
    const int lr = lane & 15, lq = lane >> 4;

    f32x4 acc[FM][FN];
#pragma unroll
    for (int i = 0; i < FM; ++i)
#pragma unroll
        for (int j = 0; j < FN; ++j) acc[i][j] = (f32x4)0.f;

    short8 pa[AIT], pw[WIT];

    auto issue = [&](int k0) {
#pragma unroll
        for (int i = 0; i < AIT; ++i) {
            const int idx = tid + i * 256;
            const int r = idx >> 3, c8 = idx & 7;
            pa[i] = *(const short8*)&A[(size_t)(row0 + r) * lda + k0 + c8 * 8];
        }
#pragma unroll
        for (int i = 0; i < WIT; ++i) {
            const int idx = tid + i * 256;
            const int r = idx >> 3, c8 = idx & 7;
            pw[i] = *(const short8*)&W[(size_t)(col0 + r) * ldw + k0 + c8 * 8];
        }
    };
    auto store = [&]() {
#pragma unroll
        for (int i = 0; i < AIT; ++i) {
            const int idx = tid + i * 256;
            const int r = idx >> 3, c8 = idx & 7;
            *(short8*)&As[r][c8 * 8] = pa[i];
        }
#pragma unroll
        for (int i = 0; i < WIT; ++i) {
            const int idx = tid + i * 256;
            const int r = idx >> 3, c8 = idx & 7;
            *(short8*)&Bs[r][c8 * 8] = pw[i];
        }
    };

    issue(0);
    store();
    const int NC = K / BK;
    for (int c = 0; c < NC; ++c) {
        if (c + 1 < NC) issue((c + 1) * BK);
        __syncthreads();
#pragma unroll
        for (int ks = 0; ks < 2; ++ks) {
            short8 af[FM], bf[FN];
#pragma unroll
            for (int i = 0; i < FM; ++i)
                af[i] = *(const short8*)&As[wr * SM + i * 16 + lr][ks * 32 + lq * 8];
#pragma unroll
            for (int j = 0; j < FN; ++j)
                bf[j] = *(const short8*)&Bs[wc * SN + j * 16 + lr][ks * 32 + lq * 8];
#pragma unroll
            for (int i = 0; i < FM; ++i)
#pragma unroll
                for (int j = 0; j < FN; ++j)
                    acc[i][j] = __builtin_amdgcn_mfma_f32_16x16x32_bf16(
                        af[i], bf[j], acc[i][j], 0, 0, 0);
        }
        __syncthreads();
        if (c + 1 < NC) store();
    }

    // C/D layout: col = lane&15, row = (lane>>4)*4 + e
#pragma unroll
    for (int i = 0; i < FM; ++i) {
#pragma unroll
        for (int j = 0; j < FN; ++j) {
            const int colb = col0 + wc * SN + j * 16 + lr;
#pragma unroll
            for (int e = 0; e < 4; ++e) {
                const int row = row0 + wr * SM + i * 16 + lq * 4 + e;
                float v = acc[i][j][e];
                if (BIASC) v += bias[colb];
                if (BIASR) v += bias[row];
                if (RELU)  v = fmaxf(v, 0.f);
                if (OUTBF) ((unsigned short*)Cout)[(size_t)row * ldc + colb] = f2bf(v);
                else       ((float*)Cout)[(size_t)row * ldc + colb] = v;
            }
        }
    }
}

// ---------------------------------------------------------------------------
// out[n,m] += sum_{h in slice z} relu(hxT[h,n] + cmT[h,m]) * w2[h]  (+b2, z=0)
// 256 threads (4 waves), tile 64n x 64m, 4x4/thread, BK=32, split-h x4,
// double-buffered LDS w/ reg prefetch (1 barrier per chunk), fp32 atomic out.
// hxT fp32 [h][n]; cmT bf16 [h][m] (converted to fp32 during LDS stage).
// ---------------------------------------------------------------------------
__global__ __launch_bounds__(256)
void fused_out(const float* __restrict__ hxT,
               const unsigned short* __restrict__ cmT,
               const float* __restrict__ w2,
               const float* __restrict__ b2,
               float* __restrict__ out)
{
    constexpr int TN = 64, TM = 64, BK = 32;
    constexpr int KS = HID / 4, NC = KS / BK;     // 128, 4
    __shared__ __align__(16) float Hs[2][BK][TN + 4];
    __shared__ __align__(16) float Cs[2][BK][TM + 4];
    __shared__ float wsh[2][BK];

    const int tid = threadIdx.x;
    const int tx = tid & 15, ty = tid >> 4;
    const int n0 = blockIdx.x * TN;
    const int m0 = blockIdx.y * TM;
    const int kbase = blockIdx.z * KS;

    float4 ph[2];
    short8 pcv;
    float  pwv;
    const int hk = tid >> 4, hc4 = tid & 15;      // H stage coords (16 thr/row)
    const int ck = tid >> 3, cc8 = tid & 7;       // C stage coords (8 thr/row)

    auto issue = [&](int k0) {
#pragma unroll
        for (int i = 0; i < 2; ++i) {
            const int k = hk + i * 16;
            ph[i] = *(const float4*)&hxT[(size_t)(kbase + k0 + k) * N_ + n0 + hc4 * 4];
        }
        pcv = *(const short8*)&cmT[(size_t)(kbase + k0 + ck) * M_ + m0 + cc8 * 8];
        pwv = (tid < BK) ? w2[kbase + k0 + tid] : 0.f;
    };
    auto store = [&](int b) {
#pragma unroll
        for (int i = 0; i < 2; ++i)
            *(float4*)&Hs[b][hk + i * 16][hc4 * 4] = ph[i];
        float4 c0, c1;
        c0.x = bf2f((unsigned short)pcv[0]); c0.y = bf2f((unsigned short)pcv[1]);
        c0.z = bf2f((unsigned short)pcv[2]); c0.w = bf2f((unsigned short)pcv[3]);
        c1.x = bf2f((unsigned short)pcv[4]); c1.y = bf2f((unsigned short)pcv[5]);
        c1.z = bf2f((unsigned short)pcv[6]); c1.w = bf2f((unsigned short)pcv[7]);
        *(float4*)&Cs[b][ck][cc8 * 8]     = c0;
        *(float4*)&Cs[b][ck][cc8 * 8 + 4] = c1;
        if (tid < BK) wsh[b][tid] = pwv;
    };

    float acc[4][4];
#pragma unroll
    for (int i = 0; i < 4; ++i)
#pragma unroll
        for (int j = 0; j < 4; ++j) acc[i][j] = 0.f;

    issue(0);
    store(0);

    for (int c = 0; c < NC; ++c) {
        const int buf = c & 1;
        if (c + 1 < NC) issue((c + 1) * BK);
        __syncthreads();
#pragma unroll
        for (int h = 0; h < BK; ++h) {
            const float4 a  = *(const float4*)&Hs[buf][h][ty * 4];
            const float4 bq = *(const float4*)&Cs[buf][h][tx * 4];
            const float wh = wsh[buf][h];
            const float av[4] = {a.x, a.y, a.z, a.w};
            const float bv[4] = {bq.x, bq.y, bq.z, bq.w};
#pragma unroll
            for (int i = 0; i < 4; ++i)
#pragma unroll
                for (int j = 0; j < 4; ++j)
                    acc[i][j] = fmaf(fmaxf(av[i] + bv[j], 0.f), wh, acc[i][j]);
        }
        if (c + 1 < NC) store((c + 1) & 1);
    }

    const float bb = (blockIdx.z == 0) ? b2[0] : 0.f;
#pragma unroll
    for (int i = 0; i < 4; ++i)
#pragma unroll
        for (int j = 0; j < 4; ++j)
            atomicAdd(&out[(size_t)(n0 + ty * 4 + i) * M_ + m0 + tx * 4 + j],
                      acc[i][j] + bb);
}

// ---------------------------------------------------------------------------
extern "C" void kernel_launch(void* const* d_in, const int* in_sizes, int n_in,
                              void* d_out, int out_size, void* d_ws, size_t ws_size,
                              hipStream_t stream)
{
    const float* x      = (const float*)d_in[0];
    const int*   tuples = (const int*)d_in[1];
    const float* Wa     = (const float*)d_in[2];
    const float* ba     = (const float*)d_in[3];
    const float* Wb     = (const float*)d_in[4];
    const float* bb     = (const float*)d_in[5];
    const float* E_pred = (const float*)d_in[6];
    const float* E_filt = (const float*)d_in[7];
    const float* E_reo  = (const float*)d_in[8];
    const float* W1     = (const float*)d_in[9];
    const float* b1     = (const float*)d_in[10];
    const float* W2     = (const float*)d_in[11];
    const float* b2     = (const float*)d_in[12];
    float* out = (float*)d_out;

    // ws layout (bytes). hxT (4 MB fp32) overlays x_bf+h_x_bf (dead by then).
    char* w = (char*)d_ws;
    unsigned short* x_bf     = (unsigned short*)(w + 0);        // 2 MB
    unsigned short* h_x_bf   = (unsigned short*)(w + 2097152);  // 2 MB
    float*          hxT      = (float*)(w + 0);                 // 4 MB (overlay)
    unsigned short* cmT_bf   = (unsigned short*)(w + 4194304);  // 256 KB
    unsigned short* x_emb_bf = (unsigned short*)(w + 4456448);  // 1 MB
    unsigned short* Wa_bf    = (unsigned short*)(w + 5505024);  // 512 KB
    unsigned short* Wb_bf    = (unsigned short*)(w + 6029312);  // 256 KB
    unsigned short* W1x_bf   = (unsigned short*)(w + 6291456);  // 256 KB
    unsigned short* W1t_bf   = (unsigned short*)(w + 6553600);  // 256 KB
    unsigned short* t_emb_bf = (unsigned short*)(w + 6815744);  // 128 KB

    hipMemsetAsync(d_out, 0, (size_t)N_ * M_ * sizeof(float), stream);

    prep<<<dim3(1728), dim3(256), 0, stream>>>(
        x, Wa, Wb, W1, tuples, E_pred, E_filt, E_reo,
        x_bf, Wa_bf, Wb_bf, W1x_bf, W1t_bf, t_emb_bf);

    // h_x = relu(x @ Wa^T + ba)   (2048x512, K=512) grid 32x8
    gemm_bf16<64, 64, true, true, true, false>
        <<<dim3(N_ / 64, HID / 64), 256, 0, stream>>>(
        x_bf, IN_DIM, Wa_bf, IN_DIM, ba, h_x_bf, HID, IN_DIM);

    // x_emb = relu(h_x @ Wb^T + bb)  (2048x256, K=512) grid 32x8
    gemm_bf16<64, 32, true, true, true, false>
        <<<dim3(N_ / 64, EMB / 32), 256, 0, stream>>>(
        h_x_bf, HID, Wb_bf, HID, bb, x_emb_bf, EMB, HID);

    // cmT[h,m] = sum_d W1t[h,d]*t_emb[m,d] + b1[h]  (512x256, K=256) grid 8x4
    gemm_bf16<64, 64, true, false, false, true>
        <<<dim3(HID / 64, M_ / 64), 256, 0, stream>>>(
        W1t_bf, EMB, t_emb_bf, EMB, b1, cmT_bf, M_, EMB);

    // hxT[h,n] = sum_d W1x[h,d]*x_emb[n,d]  (512x2048, K=256) grid 8x32
    gemm_bf16<64, 64, false, false, false, false>
        <<<dim3(HID / 64, N_ / 64), 256, 0, stream>>>(
        W1x_bf, EMB, x_emb_bf, EMB, nullptr, hxT, N_, EMB);

    // out[n,m] = sum_h relu(hxT[h,n] + cmT[h,m]) * W2[h] + b2
    fused_out<<<dim3(N_ / 64, M_ / 64, 4), 256, 0, stream>>>(
        hxT, cmT_bf, W2, b2, out);
}

// Round 5
// 120.824 us; speedup vs baseline: 1.8289x; 1.3597x over previous
//
#include <hip/hip_runtime.h>

constexpr int N_     = 2048;
constexpr int IN_DIM = 512;
constexpr int HID    = 512;
constexpr int EMB    = 256;
constexpr int M_     = 256;

typedef __attribute__((ext_vector_type(8))) short short8;
typedef __attribute__((ext_vector_type(4))) float f32x4;
typedef __attribute__((ext_vector_type(2))) _Float16 h2v;

union U32H2 { unsigned int u; h2v v; };

__device__ __forceinline__ unsigned short f2bf(float f) {
    union { float f; unsigned int u; } v; v.f = f;
    return (unsigned short)((v.u + 0x7fffu + ((v.u >> 16) & 1u)) >> 16);
}
__device__ __forceinline__ unsigned int packh2(float a, float b) {
    U32H2 r; r.v[0] = (_Float16)a; r.v[1] = (_Float16)b; return r.u;
}
__device__ __forceinline__ h2v relu2(h2v s) {
#if defined(__has_builtin) && __has_builtin(__builtin_elementwise_max)
    U32H2 z; z.u = 0u;
    return __builtin_elementwise_max(s, z.v);
#else
    U32H2 t; t.v = s;
    const unsigned int m = ((t.u & 0x80000000u) ? 0xFFFF0000u : 0u) |
                           ((t.u & 0x00008000u) ? 0x0000FFFFu : 0u);
    t.u &= ~m;
    return t.v;
#endif
}

// ---------------------------------------------------------------------------
// prep: fp32->bf16 of x,Wa,Wb,W1(split) + t_emb gather (bf16) + w2 f16-pairs.
// ---------------------------------------------------------------------------
__global__ __launch_bounds__(256)
void prep(const float* __restrict__ x, const float* __restrict__ Wa,
          const float* __restrict__ Wb, const float* __restrict__ W1,
          const int* __restrict__ tuples, const float* __restrict__ Ep,
          const float* __restrict__ Ef, const float* __restrict__ Er,
          const float* __restrict__ w2,
          unsigned short* __restrict__ x_bf, unsigned short* __restrict__ Wa_bf,
          unsigned short* __restrict__ Wb_bf, unsigned short* __restrict__ W1x_bf,
          unsigned short* __restrict__ W1t_bf, unsigned short* __restrict__ t_emb_bf,
          unsigned int* __restrict__ w2p)
{
    const int b = blockIdx.x, t = threadIdx.x;
    if (b < 1664) {
        int q = b * 256 + t;
        float4 v; ushort4 u;
        if (q < 262144) {                       // x: 2048x512
            v = ((const float4*)x)[q];
            u.x = f2bf(v.x); u.y = f2bf(v.y); u.z = f2bf(v.z); u.w = f2bf(v.w);
            ((ushort4*)x_bf)[q] = u;
        } else if ((q -= 262144) < 65536) {     // Wa: 512x512
            v = ((const float4*)Wa)[q];
            u.x = f2bf(v.x); u.y = f2bf(v.y); u.z = f2bf(v.z); u.w = f2bf(v.w);
            ((ushort4*)Wa_bf)[q] = u;
        } else if ((q -= 65536) < 32768) {      // Wb: 256x512
            v = ((const float4*)Wb)[q];
            u.x = f2bf(v.x); u.y = f2bf(v.y); u.z = f2bf(v.z); u.w = f2bf(v.w);
            ((ushort4*)Wb_bf)[q] = u;
        } else {                                // W1: 512x512 -> W1x | W1t
            q -= 32768;
            v = ((const float4*)W1)[q];
            u.x = f2bf(v.x); u.y = f2bf(v.y); u.z = f2bf(v.z); u.w = f2bf(v.w);
            const int row = q >> 7, c = (q & 127) * 4;
            if (c < 256) ((ushort4*)W1x_bf)[(row * 256 + c) >> 2] = u;
            else         ((ushort4*)W1t_bf)[(row * 256 + c - 256) >> 2] = u;
        }
    } else if (b < 1728) {                      // t_emb gather
        const int idx = (b - 1664) * 256 + t;   // 0..16383
        const int m = idx >> 6, q = idx & 63;
        const int t0 = tuples[m * 3 + 0];
        const int t1 = tuples[m * 3 + 1];
        const int t2 = tuples[m * 3 + 2];
        const float4 a = ((const float4*)(Ep + t0 * EMB))[q];
        const float4 c = ((const float4*)(Ef + t1 * EMB))[q];
        const float4 d = ((const float4*)(Er + t2 * EMB))[q];
        ushort4 u;
        u.x = f2bf(a.x + c.x + d.x);
        u.y = f2bf(a.y + c.y + d.y);
        u.z = f2bf(a.z + c.z + d.z);
        u.w = f2bf(a.w + c.w + d.w);
        ((ushort4*)t_emb_bf)[m * 64 + q] = u;
    } else {                                    // w2 -> f16 pairs (256)
        w2p[t] = packh2(w2[2 * t], w2[2 * t + 1]);
    }
}

// ---------------------------------------------------------------------------
// bf16-MFMA NT GEMM (bf16 out): C[r,c] = act( sum_k A[r,k]*W[c,k] + bias[c] )
// 256 thr = 4 waves (2x2), BK=64, reg-prefetch single LDS buffer.
// ---------------------------------------------------------------------------
template<int BM, int BN, bool RELU, bool BIASC>
__global__ __launch_bounds__(256)
void gemm_bf16(const unsigned short* __restrict__ A, int lda,
               const unsigned short* __restrict__ W, int ldw,
               const float* __restrict__ bias,
               unsigned short* __restrict__ Cout, int ldc, int K)
{
    constexpr int BK = 64;
    constexpr int SM = BM / 2, SN = BN / 2;
    constexpr int FM = SM / 16, FN = SN / 16;
    constexpr int AIT = BM / 32, WIT = BN / 32;
    __shared__ unsigned short As[BM][BK + 8];
    __shared__ unsigned short Bs[BN][BK + 8];

    const int tid  = threadIdx.x;
    const int row0 = blockIdx.x * BM, col0 = blockIdx.y * BN;
    const int wv = tid >> 6, lane = tid & 63;
    const int wr = wv >> 1, wc = wv & 1;
    const int lr = lane & 15, lq = lane >> 4;

    f32x4 acc[FM][FN];
#pragma unroll
    for (int i = 0; i < FM; ++i)
#pragma unroll
        for (int j = 0; j < FN; ++j) acc[i][j] = (f32x4)0.f;

    short8 pa[AIT], pw[WIT];
    auto issue = [&](int k0) {
#pragma unroll
        for (int i = 0; i < AIT; ++i) {
            const int idx = tid + i * 256, r = idx >> 3, c8 = idx & 7;
            pa[i] = *(const short8*)&A[(size_t)(row0 + r) * lda + k0 + c8 * 8];
        }
#pragma unroll
        for (int i = 0; i < WIT; ++i) {
            const int idx = tid + i * 256, r = idx >> 3, c8 = idx & 7;
            pw[i] = *(const short8*)&W[(size_t)(col0 + r) * ldw + k0 + c8 * 8];
        }
    };
    auto store = [&]() {
#pragma unroll
        for (int i = 0; i < AIT; ++i) {
            const int idx = tid + i * 256, r = idx >> 3, c8 = idx & 7;
            *(short8*)&As[r][c8 * 8] = pa[i];
        }
#pragma unroll
        for (int i = 0; i < WIT; ++i) {
            const int idx = tid + i * 256, r = idx >> 3, c8 = idx & 7;
            *(short8*)&Bs[r][c8 * 8] = pw[i];
        }
    };

    issue(0); store();
    const int NC = K / BK;
    for (int c = 0; c < NC; ++c) {
        if (c + 1 < NC) issue((c + 1) * BK);
        __syncthreads();
#pragma unroll
        for (int ks = 0; ks < 2; ++ks) {
            short8 af[FM], bfr[FN];
#pragma unroll
            for (int i = 0; i < FM; ++i)
                af[i] = *(const short8*)&As[wr * SM + i * 16 + lr][ks * 32 + lq * 8];
#pragma unroll
            for (int j = 0; j < FN; ++j)
                bfr[j] = *(const short8*)&Bs[wc * SN + j * 16 + lr][ks * 32 + lq * 8];
#pragma unroll
            for (int i = 0; i < FM; ++i)
#pragma unroll
                for (int j = 0; j < FN; ++j)
                    acc[i][j] = __builtin_amdgcn_mfma_f32_16x16x32_bf16(
                        af[i], bfr[j], acc[i][j], 0, 0, 0);
        }
        __syncthreads();
        if (c + 1 < NC) store();
    }

#pragma unroll
    for (int i = 0; i < FM; ++i) {
#pragma unroll
        for (int j = 0; j < FN; ++j) {
            const int colb = col0 + wc * SN + j * 16 + lr;
#pragma unroll
            for (int e = 0; e < 4; ++e) {
                const int row = row0 + wr * SM + i * 16 + lq * 4 + e;
                float v = acc[i][j][e];
                if (BIASC) v += bias[colb];
                if (RELU)  v = fmaxf(v, 0.f);
                Cout[(size_t)row * ldc + colb] = f2bf(v);
            }
        }
    }
}

// ---------------------------------------------------------------------------
// Dual GEMM for hxT/cmT: rows = h (A-operand W1x/W1t), cols = n/m.
// Output: f16 h-PAIRS packed as u32: outp[h/2][col]. BM=32, BN=64.
// blockIdx.y < 32 -> hxT (B=x_emb, 2048 cols);  >=32 -> cmT (B=t_emb, +b1).
// ---------------------------------------------------------------------------
__global__ __launch_bounds__(256)
void gemm_pair(const unsigned short* __restrict__ W1x_bf,
               const unsigned short* __restrict__ W1t_bf,
               const unsigned short* __restrict__ x_emb_bf,
               const unsigned short* __restrict__ t_emb_bf,
               const float* __restrict__ b1,
               unsigned int* __restrict__ hxT_p,
               unsigned int* __restrict__ cmT_p)
{
    constexpr int BM = 32, BN = 64, BK = 64;
    constexpr int SM = 16, SN = 32, FN = 2;
    __shared__ unsigned short As[BM][BK + 8];
    __shared__ unsigned short Bs[BN][BK + 8];

    const unsigned short* A; const unsigned short* B;
    const float* bias; unsigned int* outp; int ldc, col0;
    if (blockIdx.y < 32) {
        A = W1x_bf; B = x_emb_bf; bias = nullptr; outp = hxT_p;
        ldc = N_; col0 = blockIdx.y * BN;
    } else {
        A = W1t_bf; B = t_emb_bf; bias = b1; outp = cmT_p;
        ldc = M_; col0 = (blockIdx.y - 32) * BN;
    }
    const int K = EMB, row0 = blockIdx.x * BM;

    const int tid = threadIdx.x;
    const int wv = tid >> 6, lane = tid & 63;
    const int wr = wv >> 1, wc = wv & 1;
    const int lr = lane & 15, lq = lane >> 4;

    f32x4 acc[FN];
#pragma unroll
    for (int j = 0; j < FN; ++j) acc[j] = (f32x4)0.f;

    short8 pa, pw[2];
    auto issue = [&](int k0) {
        { const int r = tid >> 3, c8 = tid & 7;
          pa = *(const short8*)&A[(size_t)(row0 + r) * K + k0 + c8 * 8]; }
#pragma unroll
        for (int i = 0; i < 2; ++i) {
            const int idx = tid + i * 256, r = idx >> 3, c8 = idx & 7;
            pw[i] = *(const short8*)&B[(size_t)(col0 + r) * K + k0 + c8 * 8];
        }
    };
    auto store = [&]() {
        { const int r = tid >> 3, c8 = tid & 7;
          *(short8*)&As[r][c8 * 8] = pa; }
#pragma unroll
        for (int i = 0; i < 2; ++i) {
            const int idx = tid + i * 256, r = idx >> 3, c8 = idx & 7;
            *(short8*)&Bs[r][c8 * 8] = pw[i];
        }
    };

    issue(0); store();
    const int NC = K / BK;  // 4
    for (int c = 0; c < NC; ++c) {
        if (c + 1 < NC) issue((c + 1) * BK);
        __syncthreads();
#pragma unroll
        for (int ks = 0; ks < 2; ++ks) {
            short8 af, bfr[FN];
            af = *(const short8*)&As[wr * SM + lr][ks * 32 + lq * 8];
#pragma unroll
            for (int j = 0; j < FN; ++j)
                bfr[j] = *(const short8*)&Bs[wc * SN + j * 16 + lr][ks * 32 + lq * 8];
#pragma unroll
            for (int j = 0; j < FN; ++j)
                acc[j] = __builtin_amdgcn_mfma_f32_16x16x32_bf16(
                    af, bfr[j], acc[j], 0, 0, 0);
        }
        __syncthreads();
        if (c + 1 < NC) store();
    }

    // rows (h) pair-packed: rowb = row0 + wr*16 + lq*4 (multiple of 4)
    const int rowb = row0 + wr * SM + lq * 4;
#pragma unroll
    for (int j = 0; j < FN; ++j) {
        const int colb = col0 + wc * SN + j * 16 + lr;
#pragma unroll
        for (int e2 = 0; e2 < 2; ++e2) {
            float v0 = acc[j][2 * e2], v1 = acc[j][2 * e2 + 1];
            if (bias) { v0 += bias[rowb + 2 * e2]; v1 += bias[rowb + 2 * e2 + 1]; }
            outp[(size_t)((rowb >> 1) + e2) * ldc + colb] = packh2(v0, v1);
        }
    }
}

// ---------------------------------------------------------------------------
// part[z][n][m] (f16) = sum_{h2 in z} relu(hx_pair + cm_pair) . w2_pair
// Tile 64n x 32m, z=4 split (64 h2 each), single LDS load, 1024 blocks,
// 4 waves/SIMD. Packed f16: pk_add + pk_max + pk_fma, f32 dump every 8 h2.
// ---------------------------------------------------------------------------
__global__ __launch_bounds__(256, 4)
void fused_out(const unsigned int* __restrict__ hxT_p,   // [256][2048]
               const unsigned int* __restrict__ cmT_p,   // [256][256]
               const unsigned int* __restrict__ w2p,     // [256]
               unsigned int* __restrict__ part_u32)      // f16 [4][2048][256]
{
    constexpr int TN = 64, TM = 32, H2B = 64;
    __shared__ unsigned int Hs[H2B][TN + 4];
    __shared__ unsigned int Cs[H2B][TM + 4];
    __shared__ unsigned int Wsh[H2B];

    const int tid = threadIdx.x;
    const int tx = tid & 15, ty = tid >> 4;
    const int n0 = blockIdx.x * TN;
    const int m0 = blockIdx.y * TM;
    const int z  = blockIdx.z;
    const int kb = z * H2B;

#pragma unroll
    for (int p = 0; p < 4; ++p) {
        const int idx = tid + p * 256, r = idx >> 4, c4 = idx & 15;
        *(uint4*)&Hs[r][c4 * 4] =
            *(const uint4*)&hxT_p[(size_t)(kb + r) * N_ + n0 + c4 * 4];
    }
#pragma unroll
    for (int p = 0; p < 2; ++p) {
        const int idx = tid + p * 256, r = idx >> 3, c4 = idx & 7;
        *(uint4*)&Cs[r][c4 * 4] =
            *(const uint4*)&cmT_p[(size_t)(kb + r) * M_ + m0 + c4 * 4];
    }
    if (tid < H2B) Wsh[tid] = w2p[kb + tid];
    __syncthreads();

    float accf[4][2];
    U32H2 facc[4][2];
#pragma unroll
    for (int i = 0; i < 4; ++i)
#pragma unroll
        for (int j = 0; j < 2; ++j) { accf[i][j] = 0.f; facc[i][j].u = 0u; }

#pragma unroll
    for (int hb = 0; hb < H2B / 8; ++hb) {
#pragma unroll
        for (int hh = 0; hh < 8; ++hh) {
            const int h = hb * 8 + hh;
            const uint4 av = *(const uint4*)&Hs[h][ty * 4];
            const uint2 bv = *(const uint2*)&Cs[h][tx * 2];
            U32H2 w; w.u = Wsh[h];
            U32H2 a[4], b[2];
            a[0].u = av.x; a[1].u = av.y; a[2].u = av.z; a[3].u = av.w;
            b[0].u = bv.x; b[1].u = bv.y;
#pragma unroll
            for (int i = 0; i < 4; ++i) {
#pragma unroll
                for (int j = 0; j < 2; ++j) {
                    const h2v s = relu2(a[i].v + b[j].v);
                    facc[i][j].v = s * w.v + facc[i][j].v;
                }
            }
        }
#pragma unroll
        for (int i = 0; i < 4; ++i)
#pragma unroll
            for (int j = 0; j < 2; ++j) {
                accf[i][j] += (float)facc[i][j].v[0] + (float)facc[i][j].v[1];
                facc[i][j].u = 0u;
            }
    }

    // write f16 partials: m-pair (m0+2tx, m0+2tx+1) per n-row
#pragma unroll
    for (int i = 0; i < 4; ++i) {
        const int n = n0 + ty * 4 + i;
        part_u32[((size_t)z * N_ + n) * (M_ / 2) + (m0 >> 1) + tx] =
            packh2(accf[i][0], accf[i][1]);
    }
}

// ---------------------------------------------------------------------------
// out[n,m] = b2 + sum_z part[z][n][m]
// ---------------------------------------------------------------------------
__global__ __launch_bounds__(256)
void reduce_out(const unsigned short* __restrict__ part,
                const float* __restrict__ b2,
                float* __restrict__ out)
{
    const int g = blockIdx.x * 256 + threadIdx.x;   // 65536
    const int n = g >> 5;
    const int m0 = (g & 31) * 8;
    const float bb = b2[0];
    float s[8];
#pragma unroll
    for (int i = 0; i < 8; ++i) s[i] = bb;
#pragma unroll
    for (int zz = 0; zz < 4; ++zz) {
        const uint4 v = *(const uint4*)&part[((size_t)zz * N_ + n) * M_ + m0];
        const unsigned int vv[4] = {v.x, v.y, v.z, v.w};
#pragma unroll
        for (int q = 0; q < 4; ++q) {
            U32H2 u; u.u = vv[q];
            s[2 * q]     += (float)u.v[0];
            s[2 * q + 1] += (float)u.v[1];
        }
    }
    float4 o0 = {s[0], s[1], s[2], s[3]};
    float4 o1 = {s[4], s[5], s[6], s[7]};
    *(float4*)&out[(size_t)n * M_ + m0]     = o0;
    *(float4*)&out[(size_t)n * M_ + m0 + 4] = o1;
}

// ---------------------------------------------------------------------------
extern "C" void kernel_launch(void* const* d_in, const int* in_sizes, int n_in,
                              void* d_out, int out_size, void* d_ws, size_t ws_size,
                              hipStream_t stream)
{
    const float* x      = (const float*)d_in[0];
    const int*   tuples = (const int*)d_in[1];
    const float* Wa     = (const float*)d_in[2];
    const float* ba     = (const float*)d_in[3];
    const float* Wb     = (const float*)d_in[4];
    const float* bb     = (const float*)d_in[5];
    const float* E_pred = (const float*)d_in[6];
    const float* E_filt = (const float*)d_in[7];
    const float* E_reo  = (const float*)d_in[8];
    const float* W1     = (const float*)d_in[9];
    const float* b1     = (const float*)d_in[10];
    const float* W2     = (const float*)d_in[11];
    const float* b2     = (const float*)d_in[12];
    float* out = (float*)d_out;

    // ws layout (byte offsets), peak ~6.63 MB:
    //  0      .. 2M   : x_bf (prep->g1)        | hxT_p (g34->fused)
    //  2M     .. 4M   : h_x_bf (g1->g2)        | part[0..2M] (fused->reduce)
    //  4M     .. 5M   : x_emb_bf (g2->g34)     | part[2M..3M]
    //  5M     .. 5.5M : Wa_bf (prep->g1)       | part[3M..3.5M]
    //  5.5M   .. 5.75M: Wb_bf (prep->g2)       | part[3.5..3.75M]
    //  5.75M  .. 6M   : W1x_bf (prep->g34)     | part[3.75..4M]
    //  6M     .. 6.25M: cmT_p (g34->fused)
    //  6.25M  .. 6.5M : W1t_bf (prep->g34)
    //  6.5M   .. 6.625M: t_emb_bf (prep->g34)
    //  6.625M .. +1K  : w2p (prep->fused)
    char* w = (char*)d_ws;
    unsigned short* x_bf     = (unsigned short*)(w + 0);
    unsigned int*   hxT_p    = (unsigned int*)(w + 0);
    unsigned short* h_x_bf   = (unsigned short*)(w + 2097152);
    unsigned int*   part_u32 = (unsigned int*)(w + 2097152);
    unsigned short* x_emb_bf = (unsigned short*)(w + 4194304);
    unsigned short* Wa_bf    = (unsigned short*)(w + 5242880);
    unsigned short* Wb_bf    = (unsigned short*)(w + 5767168);
    unsigned short* W1x_bf   = (unsigned short*)(w + 6029312);
    unsigned int*   cmT_p    = (unsigned int*)(w + 6291456);
    unsigned short* W1t_bf   = (unsigned short*)(w + 6553600);
    unsigned short* t_emb_bf = (unsigned short*)(w + 6815744);
    unsigned int*   w2p      = (unsigned int*)(w + 6946816);

    prep<<<dim3(1729), dim3(256), 0, stream>>>(
        x, Wa, Wb, W1, tuples, E_pred, E_filt, E_reo, W2,
        x_bf, Wa_bf, Wb_bf, W1x_bf, W1t_bf, t_emb_bf, w2p);

    // h_x = relu(x @ Wa^T + ba)   (2048x512, K=512) grid 64x8
    gemm_bf16<32, 64, true, true><<<dim3(N_ / 32, HID / 64), 256, 0, stream>>>(
        x_bf, IN_DIM, Wa_bf, IN_DIM, ba, h_x_bf, HID, IN_DIM);

    // x_emb = relu(h_x @ Wb^T + bb)  (2048x256, K=512) grid 64x8
    gemm_bf16<32, 32, true, true><<<dim3(N_ / 32, EMB / 32), 256, 0, stream>>>(
        h_x_bf, HID, Wb_bf, HID, bb, x_emb_bf, EMB, HID);

    // hxT_p[h2][n] & cmT_p[h2][m] (f16 h-pairs), merged: grid 16 x (32+4)
    gemm_pair<<<dim3(HID / 32, 36), 256, 0, stream>>>(
        W1x_bf, W1t_bf, x_emb_bf, t_emb_bf, b1, hxT_p, cmT_p);

    // partials over z=4 h-slices
    fused_out<<<dim3(N_ / 64, M_ / 32, 4), 256, 0, stream>>>(
        hxT_p, cmT_p, w2p, part_u32);

    // out = b2 + sum_z part
    reduce_out<<<dim3(65536 / 256), 256, 0, stream>>>(
        (const unsigned short*)part_u32, b2, out);
}